// Round 5
// baseline (450.651 us; speedup 1.0000x reference)
//
#include <hip/hip_runtime.h>
#include <stdint.h>

#define HIDDEN 1024
#define INTER 2048
#define NEXP 8
#define NE 7
#define NTOK 16384
#define CAP 2048
#define BM 64
#define BN 64
#define BK 64
#define GBM 128
#define GBN 128

typedef __attribute__((ext_vector_type(8))) short short8;
typedef __attribute__((ext_vector_type(4))) float f32x4;

__device__ __forceinline__ unsigned short f2bf(float f) {
  union { float f; unsigned int u; } v;
  v.f = f;
  unsigned int u = v.u;
  unsigned int r = (u + 0x7FFFu + ((u >> 16) & 1u)) >> 16;  // RNE
  return (unsigned short)r;
}

typedef __attribute__((address_space(1))) const unsigned int gu32;
typedef __attribute__((address_space(3))) unsigned int lu32;
__device__ __forceinline__ void gload16(const void* g, void* l) {
  __builtin_amdgcn_global_load_lds((gu32*)g, (lu32*)l, 16, 0, 0);
}

// ============ fused prologue: router + x->bf16 + noop out-init ============
__global__ __launch_bounds__(256) void prologue_kernel(
    const float* __restrict__ x, const float* __restrict__ rw,
    const float* __restrict__ rb, float* __restrict__ expw,
    float* __restrict__ noopw, unsigned short* __restrict__ xbf,
    float* __restrict__ out) {
  if (blockIdx.x == NTOK / 4) {
    unsigned int* z = (unsigned int*)(xbf + (size_t)NTOK * HIDDEN);
    z[threadIdx.x] = 0u;
    z[threadIdx.x + 256] = 0u;
    return;
  }
  int wid = threadIdx.x >> 6;
  int lane = threadIdx.x & 63;
  int token = blockIdx.x * 4 + wid;
  const float* xr = x + (size_t)token * HIDDEN;
  float4 xv[4];
  float acc[NEXP];
#pragma unroll
  for (int e = 0; e < NEXP; e++) acc[e] = 0.f;
#pragma unroll
  for (int j = 0; j < 4; j++) {
    xv[j] = *(const float4*)(xr + j * 256 + lane * 4);
#pragma unroll
    for (int e = 0; e < NEXP; e++) {
      float4 wv = *(const float4*)(rw + e * HIDDEN + j * 256 + lane * 4);
      acc[e] = fmaf(xv[j].x, wv.x, acc[e]);
      acc[e] = fmaf(xv[j].y, wv.y, acc[e]);
      acc[e] = fmaf(xv[j].z, wv.z, acc[e]);
      acc[e] = fmaf(xv[j].w, wv.w, acc[e]);
    }
  }
#pragma unroll
  for (int e = 0; e < NEXP; e++) {
    float a = acc[e];
#pragma unroll
    for (int off = 32; off > 0; off >>= 1) a += __shfl_xor(a, off);
    acc[e] = a + rb[e];
  }
  float nwv = 0.f;
  if (lane == 0) {
    float m = acc[0];
#pragma unroll
    for (int e = 1; e < NEXP; e++) m = fmaxf(m, acc[e]);
    float w[NEXP];
    float s = 0.f;
#pragma unroll
    for (int e = 0; e < NEXP; e++) { w[e] = expf(acc[e] - m); s += w[e]; }
    float inv = 1.f / s;
#pragma unroll
    for (int e = 0; e < NEXP; e++) w[e] *= inv;
    int t1 = 0;
#pragma unroll
    for (int e = 1; e < NEXP; e++) if (w[e] > w[t1]) t1 = e;
    int t2 = (t1 == 0) ? 1 : 0;
#pragma unroll
    for (int e = 0; e < NEXP; e++) if (e != t1 && w[e] > w[t2]) t2 = e;
    nwv = (t1 == NEXP - 1) ? w[t1] : ((t2 == NEXP - 1) ? w[t2] : 0.f);
    noopw[token] = nwv;
#pragma unroll
    for (int e = 0; e < NE; e++) {
      float v = 0.f;
      if (e == t1) v = w[e];
      if (e == t2) v = w[e];
      expw[(size_t)e * NTOK + token] = v;
    }
  }
  float nw = __shfl(nwv, 0);
  float* orow = out + (size_t)token * HIDDEN;
  unsigned short* brow = xbf + (size_t)token * HIDDEN;
#pragma unroll
  for (int j = 0; j < 4; j++) {
    float4 o = xv[j];
    o.x *= nw; o.y *= nw; o.z *= nw; o.w *= nw;
    *(float4*)(orow + j * 256 + lane * 4) = o;
    ushort4 b;
    b.x = f2bf(xv[j].x); b.y = f2bf(xv[j].y);
    b.z = f2bf(xv[j].z); b.w = f2bf(xv[j].w);
    *(ushort4*)(brow + j * 256 + lane * 4) = b;
  }
}

// ============ parallel assign: 1024-thread block scan per expert ============
__global__ __launch_bounds__(1024) void assign_par_kernel(
    const float* __restrict__ expw, int* __restrict__ slot_tok,
    float* __restrict__ slot_w) {
  int e = blockIdx.x;
  int tid = threadIdx.x;
  int lane = tid & 63, w = tid >> 6;  // 16 waves
  __shared__ int wtot[16];
  const float* we = expw + (size_t)e * NTOK;
  int base = 0;
#pragma unroll 1
  for (int r = 0; r < NTOK / 1024; r++) {
    int t = r * 1024 + tid;
    float wv = we[t];
    bool flag = wv > 0.f;
    unsigned long long mask = __ballot(flag);
    int lp = __popcll(mask & ((1ull << lane) - 1ull));
    if (lane == 0) wtot[w] = __popcll(mask);
    __syncthreads();
    int pre = 0, tot = 0;
#pragma unroll
    for (int i = 0; i < 16; i++) {
      int v = wtot[i];
      pre += (i < w) ? v : 0;
      tot += v;
    }
    int pos = base + pre + lp;
    if (flag && pos < CAP) {
      slot_tok[e * CAP + pos] = t;
      slot_w[e * CAP + pos] = wv;
    }
    base += tot;
    __syncthreads();
    if (base >= CAP) break;  // uniform across block
  }
  int cnt = base < CAP ? base : CAP;
  for (int p = cnt + tid; p < CAP; p += 1024) {
    slot_tok[e * CAP + p] = -1;
    slot_w[e * CAP + p] = 0.f;
  }
}

// ---------------- prep: per-expert [K][N] f32 -> [N][K] bf16 ----------------
__global__ __launch_bounds__(256) void transpose_bf16_kernel(
    const float* __restrict__ in, unsigned short* __restrict__ outp,
    int K, int N) {
  int e = blockIdx.z;
  const float* src = in + (size_t)e * K * N;
  unsigned short* dst = outp + (size_t)e * K * N;
  int k0 = blockIdx.y * 64;
  int n0 = blockIdx.x * 64;
  __shared__ float tile[64][65];
  int tid = threadIdx.x;
  int nr = tid & 15;
  int kr = tid >> 4;
#pragma unroll
  for (int i = 0; i < 4; i++) {
    int k = i * 16 + kr;
    float4 v = *(const float4*)(src + (size_t)(k0 + k) * N + n0 + nr * 4);
    tile[k][nr * 4 + 0] = v.x;
    tile[k][nr * 4 + 1] = v.y;
    tile[k][nr * 4 + 2] = v.z;
    tile[k][nr * 4 + 3] = v.w;
  }
  __syncthreads();
  int g = tid & 7;
  int nb = tid >> 3;
#pragma unroll
  for (int i = 0; i < 2; i++) {
    int n = i * 32 + nb;
    short8 p;
#pragma unroll
    for (int j = 0; j < 8; j++) p[j] = (short)f2bf(tile[g * 8 + j][n]);
    *(short8*)(dst + (size_t)(n0 + n) * K + k0 + g * 8) = p;
  }
}

// ------- gemm (128x128, BK=64, global_load_lds, 2-phase LDS double-buffer) --
// Prefetch tile t+1 into the alternate buffer BEFORE computing tile t; the
// barrier's implicit vmcnt(0) drain then sees latency already elapsed.
__global__ __launch_bounds__(256) void gemm1_mfma_kernel(
    const unsigned short* __restrict__ xbf, const unsigned short* __restrict__ wiT,
    const int* __restrict__ slot_tok, unsigned short* __restrict__ h) {
  // grid (16,16,7): orig = bx + 16*by + 256*bz ; nwg=1792, chunk=224
  int orig = blockIdx.x + (blockIdx.y << 4) + (blockIdx.z << 8);
  int swz = (orig & 7) * 224 + (orig >> 3);
  int bxi = swz & 15, byi = (swz >> 4) & 15, bzi = swz >> 8;
  int e = bzi;
  const unsigned short* be = wiT + (size_t)e * HIDDEN * INTER;
  unsigned short* he = h + (size_t)e * CAP * INTER;
  int bm0 = byi * GBM;
  int bn0 = bxi * GBN;
  __shared__ __align__(16) unsigned short As[2][GBM * 64];
  __shared__ __align__(16) unsigned short Bs[2][GBN * 64];
  int tid = threadIdx.x;
  int lane = tid & 63, w = tid >> 6;
  int wm = w >> 1, wn = w & 1;

  const unsigned short* aptr[4];
  const unsigned short* bptr[4];
#pragma unroll
  for (int c = 0; c < 4; c++) {
    int s = w * 4 + c;
    int r = s * 8 + (lane >> 3);
    int gb = lane & 7;
    int g = gb ^ (r & 7);
    int tok = slot_tok[e * CAP + bm0 + r];
    int row = tok < 0 ? NTOK : tok;
    aptr[c] = xbf + (size_t)row * HIDDEN + g * 8;
    bptr[c] = be + (size_t)(bn0 + r) * HIDDEN + g * 8;
  }

  f32x4 acc[4][4];
#pragma unroll
  for (int i = 0; i < 4; i++)
#pragma unroll
    for (int j = 0; j < 4; j++) acc[i][j] = (f32x4){0.f, 0.f, 0.f, 0.f};

  auto stage = [&](int k0, unsigned short* A, unsigned short* B) {
#pragma unroll
    for (int c = 0; c < 4; c++) {
      gload16(aptr[c] + k0, A + (w * 4 + c) * 512);
      gload16(bptr[c] + k0, B + (w * 4 + c) * 512);
    }
  };
  auto compute = [&](const unsigned short* A, const unsigned short* B) {
#pragma unroll
    for (int kk = 0; kk < 2; kk++) {
      short8 a[4], b[4];
#pragma unroll
      for (int fm = 0; fm < 4; fm++) {
        int r = wm * 64 + fm * 16 + (lane & 15);
        int gb = (kk * 4 + (lane >> 4)) ^ (r & 7);
        a[fm] = *(const short8*)&A[r * 64 + gb * 8];
      }
#pragma unroll
      for (int fn = 0; fn < 4; fn++) {
        int n = wn * 64 + fn * 16 + (lane & 15);
        int gb = (kk * 4 + (lane >> 4)) ^ (n & 7);
        b[fn] = *(const short8*)&B[n * 64 + gb * 8];
      }
#pragma unroll
      for (int fm = 0; fm < 4; fm++)
#pragma unroll
        for (int fn = 0; fn < 4; fn++)
          acc[fm][fn] = __builtin_amdgcn_mfma_f32_16x16x32_bf16(
              a[fm], b[fn], acc[fm][fn], 0, 0, 0);
    }
  };

  stage(0, As[0], Bs[0]);
  __syncthreads();
#pragma unroll 1
  for (int k0 = 0; k0 < HIDDEN; k0 += 128) {
    stage(k0 + 64, As[1], Bs[1]);
    compute(As[0], Bs[0]);
    __syncthreads();
    if (k0 + 128 < HIDDEN) stage(k0 + 128, As[0], Bs[0]);
    compute(As[1], Bs[1]);
    __syncthreads();
  }
#pragma unroll
  for (int fm = 0; fm < 4; fm++)
#pragma unroll
    for (int r4 = 0; r4 < 4; r4++) {
      int m = bm0 + wm * 64 + fm * 16 + ((lane >> 4) << 2) + r4;
#pragma unroll
      for (int fn = 0; fn < 4; fn++) {
        int n = bn0 + wn * 64 + fn * 16 + (lane & 15);
        float v = acc[fm][fn][r4];
        he[(size_t)m * INTER + n] = f2bf(v > 0.f ? v : 0.f);
      }
    }
}

__global__ __launch_bounds__(256) void gemm2_mfma_kernel(
    const unsigned short* __restrict__ h, const unsigned short* __restrict__ woT,
    const int* __restrict__ slot_tok, const float* __restrict__ slot_w,
    float* __restrict__ out) {
  // grid (8,16,7): orig = bx + 8*by + 128*bz ; nwg=896, chunk=112
  int orig = blockIdx.x + (blockIdx.y << 3) + (blockIdx.z << 7);
  int swz = (orig & 7) * 112 + (orig >> 3);
  int bxi = swz & 7, byi = (swz >> 3) & 15, bzi = swz >> 7;
  int e = bzi;
  const unsigned short* ae = h + (size_t)e * CAP * INTER;
  const unsigned short* be = woT + (size_t)e * INTER * HIDDEN;  // [HIDDEN][INTER]
  int bm0 = byi * GBM;
  int bn0 = bxi * GBN;
  __shared__ __align__(16) unsigned short As[2][GBM * 64];
  __shared__ __align__(16) unsigned short Bs[2][GBN * 64];
  int tid = threadIdx.x;
  int lane = tid & 63, w = tid >> 6;
  int wm = w >> 1, wn = w & 1;

  const unsigned short* aptr[4];
  const unsigned short* bptr[4];
#pragma unroll
  for (int c = 0; c < 4; c++) {
    int s = w * 4 + c;
    int r = s * 8 + (lane >> 3);
    int gb = lane & 7;
    int g = gb ^ (r & 7);
    aptr[c] = ae + (size_t)(bm0 + r) * INTER + g * 8;
    bptr[c] = be + (size_t)(bn0 + r) * INTER + g * 8;
  }

  f32x4 acc[4][4];
#pragma unroll
  for (int i = 0; i < 4; i++)
#pragma unroll
    for (int j = 0; j < 4; j++) acc[i][j] = (f32x4){0.f, 0.f, 0.f, 0.f};

  auto stage = [&](int k0, unsigned short* A, unsigned short* B) {
#pragma unroll
    for (int c = 0; c < 4; c++) {
      gload16(aptr[c] + k0, A + (w * 4 + c) * 512);
      gload16(bptr[c] + k0, B + (w * 4 + c) * 512);
    }
  };
  auto compute = [&](const unsigned short* A, const unsigned short* B) {
#pragma unroll
    for (int kk = 0; kk < 2; kk++) {
      short8 a[4], b[4];
#pragma unroll
      for (int fm = 0; fm < 4; fm++) {
        int r = wm * 64 + fm * 16 + (lane & 15);
        int gb = (kk * 4 + (lane >> 4)) ^ (r & 7);
        a[fm] = *(const short8*)&A[r * 64 + gb * 8];
      }
#pragma unroll
      for (int fn = 0; fn < 4; fn++) {
        int n = wn * 64 + fn * 16 + (lane & 15);
        int gb = (kk * 4 + (lane >> 4)) ^ (n & 7);
        b[fn] = *(const short8*)&B[n * 64 + gb * 8];
      }
#pragma unroll
      for (int fm = 0; fm < 4; fm++)
#pragma unroll
        for (int fn = 0; fn < 4; fn++)
          acc[fm][fn] = __builtin_amdgcn_mfma_f32_16x16x32_bf16(
              a[fm], b[fn], acc[fm][fn], 0, 0, 0);
    }
  };

  stage(0, As[0], Bs[0]);
  __syncthreads();
#pragma unroll 1
  for (int k0 = 0; k0 < INTER; k0 += 128) {
    stage(k0 + 64, As[1], Bs[1]);
    compute(As[0], Bs[0]);
    __syncthreads();
    if (k0 + 128 < INTER) stage(k0 + 128, As[0], Bs[0]);
    compute(As[1], Bs[1]);
    __syncthreads();
  }
#pragma unroll
  for (int fm = 0; fm < 4; fm++)
#pragma unroll
    for (int r4 = 0; r4 < 4; r4++) {
      int m = bm0 + wm * 64 + fm * 16 + ((lane >> 4) << 2) + r4;
      int tok = slot_tok[e * CAP + m];
      float sw = slot_w[e * CAP + m];
      if (tok >= 0) {
#pragma unroll
        for (int fn = 0; fn < 4; fn++) {
          int n = bn0 + wn * 64 + fn * 16 + (lane & 15);
          unsafeAtomicAdd(out + (size_t)tok * HIDDEN + n, acc[fm][fn][r4] * sw);
        }
      }
    }
}

// ================= fallback path (round-2 64^2 kernels) =================
__global__ __launch_bounds__(256) void router_kernel(
    const float* __restrict__ x, const float* __restrict__ rw,
    const float* __restrict__ rb, float* __restrict__ expw,
    float* __restrict__ noopw) {
  int wid = threadIdx.x >> 6;
  int lane = threadIdx.x & 63;
  int token = blockIdx.x * 4 + wid;
  const float* xr = x + (size_t)token * HIDDEN;
  float acc[NEXP];
#pragma unroll
  for (int e = 0; e < NEXP; e++) acc[e] = 0.f;
#pragma unroll
  for (int j = 0; j < HIDDEN / 64; j++) {
    int k = j * 64 + lane;
    float xv = xr[k];
#pragma unroll
    for (int e = 0; e < NEXP; e++) acc[e] = fmaf(xv, rw[e * HIDDEN + k], acc[e]);
  }
#pragma unroll
  for (int e = 0; e < NEXP; e++) {
    float a = acc[e];
#pragma unroll
    for (int off = 32; off > 0; off >>= 1) a += __shfl_xor(a, off);
    acc[e] = a + rb[e];
  }
  if (lane == 0) {
    float m = acc[0];
#pragma unroll
    for (int e = 1; e < NEXP; e++) m = fmaxf(m, acc[e]);
    float w[NEXP];
    float s = 0.f;
#pragma unroll
    for (int e = 0; e < NEXP; e++) { w[e] = expf(acc[e] - m); s += w[e]; }
    float inv = 1.f / s;
#pragma unroll
    for (int e = 0; e < NEXP; e++) w[e] *= inv;
    int t1 = 0;
#pragma unroll
    for (int e = 1; e < NEXP; e++) if (w[e] > w[t1]) t1 = e;
    int t2 = (t1 == 0) ? 1 : 0;
#pragma unroll
    for (int e = 0; e < NEXP; e++) if (e != t1 && w[e] > w[t2]) t2 = e;
    noopw[token] = (t1 == NEXP - 1) ? w[t1] : ((t2 == NEXP - 1) ? w[t2] : 0.f);
#pragma unroll
    for (int e = 0; e < NE; e++) {
      float v = 0.f;
      if (e == t1) v = w[e];
      if (e == t2) v = w[e];
      expw[(size_t)e * NTOK + token] = v;
    }
  }
}

__global__ void assign_kernel(const float* __restrict__ expw,
                              int* __restrict__ slot_tok,
                              float* __restrict__ slot_w) {
  int e = blockIdx.x;
  int lane = threadIdx.x;
  const float* we = expw + (size_t)e * NTOK;
  int base = 0;
  for (int t0 = 0; t0 < NTOK; t0 += 64) {
    float w = we[t0 + lane];
    bool flag = w > 0.f;
    unsigned long long mask = __ballot(flag);
    int prefix = __popcll(mask & ((1ull << lane) - 1ull));
    int pos = base + prefix;
    if (flag && pos < CAP) {
      slot_tok[e * CAP + pos] = t0 + lane;
      slot_w[e * CAP + pos] = w;
    }
    base += __popcll(mask);
    if (base >= CAP) break;
  }
  int cnt = base < CAP ? base : CAP;
  for (int p = cnt + lane; p < CAP; p += 64) {
    slot_tok[e * CAP + p] = -1;
    slot_w[e * CAP + p] = 0.f;
  }
}

__global__ __launch_bounds__(256) void noop_kernel(
    const float* __restrict__ x, const float* __restrict__ noopw,
    float* __restrict__ out) {
  size_t i = (size_t)blockIdx.x * 256 + threadIdx.x;
  float4 v = ((const float4*)x)[i];
  float w = noopw[i >> 8];
  v.x *= w; v.y *= w; v.z *= w; v.w *= w;
  ((float4*)out)[i] = v;
}

__global__ __launch_bounds__(256) void gemm1_kernel(
    const float* __restrict__ x, const float* __restrict__ wi,
    const int* __restrict__ slot_tok, unsigned short* __restrict__ h,
    int e_base) {
  int e = e_base + blockIdx.z;
  unsigned short* he = h + (size_t)blockIdx.z * ((size_t)CAP * INTER);
  const float* wie = wi + (size_t)e * HIDDEN * INTER;
  int bm0 = blockIdx.y * BM;
  int bn0 = blockIdx.x * BN;
  __shared__ __align__(16) unsigned short As[BM][BK];
  __shared__ __align__(16) unsigned short Bs[BN][BK];
  int tid = threadIdx.x;
  int lane = tid & 63;
  int wid = tid >> 6;
  int wm = wid >> 1, wn = wid & 1;
  int tokA[2];
#pragma unroll
  for (int t = 0; t < 2; t++)
    tokA[t] = slot_tok[e * CAP + bm0 + ((tid + t * 256) >> 3)];
  f32x4 acc[2][2];
#pragma unroll
  for (int i = 0; i < 2; i++)
#pragma unroll
    for (int j = 0; j < 2; j++) acc[i][j] = (f32x4){0.f, 0.f, 0.f, 0.f};
  for (int k0 = 0; k0 < HIDDEN; k0 += BK) {
#pragma unroll
    for (int t = 0; t < 2; t++) {
      int idx = tid + t * 256;
      int r = idx >> 3, g = idx & 7;
      short8 pack;
      if (tokA[t] >= 0) {
        const float* src = x + (size_t)tokA[t] * HIDDEN + k0 + g * 8;
        float4 v0 = ((const float4*)src)[0];
        float4 v1 = ((const float4*)src)[1];
        pack[0] = (short)f2bf(v0.x); pack[1] = (short)f2bf(v0.y);
        pack[2] = (short)f2bf(v0.z); pack[3] = (short)f2bf(v0.w);
        pack[4] = (short)f2bf(v1.x); pack[5] = (short)f2bf(v1.y);
        pack[6] = (short)f2bf(v1.z); pack[7] = (short)f2bf(v1.w);
      } else {
        pack = (short8){0, 0, 0, 0, 0, 0, 0, 0};
      }
      int gs = g ^ (r & 7);
      *(short8*)(&As[r][gs * 8]) = pack;
    }
#pragma unroll
    for (int t = 0; t < 2; t++) {
      int idx = tid + t * 256;
      int k = idx >> 3, g = idx & 7;
      const float* src = wie + (size_t)(k0 + k) * INTER + bn0 + g * 8;
      float4 v0 = ((const float4*)src)[0];
      float4 v1 = ((const float4*)src)[1];
      float f[8] = {v0.x, v0.y, v0.z, v0.w, v1.x, v1.y, v1.z, v1.w};
#pragma unroll
      for (int i2 = 0; i2 < 8; i2++) {
        int n = g * 8 + i2;
        int kc = k ^ ((n & 7) << 3);
        Bs[n][kc] = f2bf(f[i2]);
      }
    }
    __syncthreads();
#pragma unroll
    for (int kk = 0; kk < 2; kk++) {
      short8 a[2], b[2];
#pragma unroll
      for (int fm = 0; fm < 2; fm++) {
        int r = wm * 32 + fm * 16 + (lane & 15);
        int gs = (kk * 4 + (lane >> 4)) ^ (r & 7);
        a[fm] = *(const short8*)(&As[r][gs * 8]);
      }
#pragma unroll
      for (int fn = 0; fn < 2; fn++) {
        int n = wn * 32 + fn * 16 + (lane & 15);
        int gs = (kk * 4 + (lane >> 4)) ^ (n & 7);
        b[fn] = *(const short8*)(&Bs[n][gs * 8]);
      }
#pragma unroll
      for (int fm = 0; fm < 2; fm++)
#pragma unroll
        for (int fn = 0; fn < 2; fn++)
          acc[fm][fn] = __builtin_amdgcn_mfma_f32_16x16x32_bf16(
              a[fm], b[fn], acc[fm][fn], 0, 0, 0);
    }
    __syncthreads();
  }
#pragma unroll
  for (int fm = 0; fm < 2; fm++)
#pragma unroll
    for (int fn = 0; fn < 2; fn++)
#pragma unroll
      for (int r = 0; r < 4; r++) {
        int m = bm0 + wm * 32 + fm * 16 + ((lane >> 4) << 2) + r;
        int n = bn0 + wn * 32 + fn * 16 + (lane & 15);
        float v = acc[fm][fn][r];
        v = v > 0.f ? v : 0.f;
        he[(size_t)m * INTER + n] = f2bf(v);
      }
}

__global__ __launch_bounds__(256) void gemm2_kernel(
    const unsigned short* __restrict__ h, const float* __restrict__ wo,
    const int* __restrict__ slot_tok, const float* __restrict__ slot_w,
    float* __restrict__ out, int e_base) {
  int e = e_base + blockIdx.z;
  const unsigned short* he = h + (size_t)blockIdx.z * ((size_t)CAP * INTER);
  const float* woe = wo + (size_t)e * INTER * HIDDEN;
  int bm0 = blockIdx.y * BM;
  int bn0 = blockIdx.x * BN;
  __shared__ __align__(16) unsigned short As[BM][BK];
  __shared__ __align__(16) unsigned short Bs[BN][BK];
  int tid = threadIdx.x;
  int lane = tid & 63;
  int wid = tid >> 6;
  int wm = wid >> 1, wn = wid & 1;
  f32x4 acc[2][2];
#pragma unroll
  for (int i = 0; i < 2; i++)
#pragma unroll
    for (int j = 0; j < 2; j++) acc[i][j] = (f32x4){0.f, 0.f, 0.f, 0.f};
  for (int k0 = 0; k0 < INTER; k0 += BK) {
#pragma unroll
    for (int t = 0; t < 2; t++) {
      int idx = tid + t * 256;
      int r = idx >> 3, g = idx & 7;
      short8 pack = *(const short8*)(he + (size_t)(bm0 + r) * INTER + k0 + g * 8);
      int gs = g ^ (r & 7);
      *(short8*)(&As[r][gs * 8]) = pack;
    }
#pragma unroll
    for (int t = 0; t < 2; t++) {
      int idx = tid + t * 256;
      int k = idx >> 3, g = idx & 7;
      const float* src = woe + (size_t)(k0 + k) * HIDDEN + bn0 + g * 8;
      float4 v0 = ((const float4*)src)[0];
      float4 v1 = ((const float4*)src)[1];
      float f[8] = {v0.x, v0.y, v0.z, v0.w, v1.x, v1.y, v1.z, v1.w};
#pragma unroll
      for (int i2 = 0; i2 < 8; i2++) {
        int n = g * 8 + i2;
        int kc = k ^ ((n & 7) << 3);
        Bs[n][kc] = f2bf(f[i2]);
      }
    }
    __syncthreads();
#pragma unroll
    for (int kk = 0; kk < 2; kk++) {
      short8 a[2], b[2];
#pragma unroll
      for (int fm = 0; fm < 2; fm++) {
        int r = wm * 32 + fm * 16 + (lane & 15);
        int gs = (kk * 4 + (lane >> 4)) ^ (r & 7);
        a[fm] = *(const short8*)(&As[r][gs * 8]);
      }
#pragma unroll
      for (int fn = 0; fn < 2; fn++) {
        int n = wn * 32 + fn * 16 + (lane & 15);
        int gs = (kk * 4 + (lane >> 4)) ^ (n & 7);
        b[fn] = *(const short8*)(&Bs[n][gs * 8]);
      }
#pragma unroll
      for (int fm = 0; fm < 2; fm++)
#pragma unroll
        for (int fn = 0; fn < 2; fn++)
          acc[fm][fn] = __builtin_amdgcn_mfma_f32_16x16x32_bf16(
              a[fm], b[fn], acc[fm][fn], 0, 0, 0);
    }
    __syncthreads();
  }
#pragma unroll
  for (int fm = 0; fm < 2; fm++)
#pragma unroll
    for (int r = 0; r < 4; r++) {
      int m = bm0 + wm * 32 + fm * 16 + ((lane >> 4) << 2) + r;
      int tok = slot_tok[e * CAP + m];
      float sw = slot_w[e * CAP + m];
      if (tok >= 0) {
#pragma unroll
        for (int fn = 0; fn < 2; fn++) {
          int n = bn0 + wn * 32 + fn * 16 + (lane & 15);
          unsafeAtomicAdd(out + (size_t)tok * HIDDEN + n, acc[fm][fn][r] * sw);
        }
      }
    }
}

extern "C" void kernel_launch(void* const* d_in, const int* in_sizes, int n_in,
                              void* d_out, int out_size, void* d_ws, size_t ws_size,
                              hipStream_t stream) {
  const float* x = (const float*)d_in[0];
  const float* rw = (const float*)d_in[1];
  const float* rb = (const float*)d_in[2];
  const float* wi = (const float*)d_in[3];
  const float* wo = (const float*)d_in[4];
  float* out = (float*)d_out;
  char* ws = (char*)d_ws;

  const size_t h_bytes = (size_t)NE * CAP * INTER * 2;            // 58,720,256
  const size_t xbf_bytes = (size_t)(NTOK + 1) * HIDDEN * 2;       // 33,556,480
  const size_t wT_bytes = (size_t)NE * HIDDEN * INTER * 2;        // 29,360,128
  const size_t P_bytes = xbf_bytes + wT_bytes;                    // 62,916,608
  const size_t small_bytes = (size_t)NE * NTOK * 4 + (size_t)NTOK * 4 +
                             (size_t)NE * CAP * 4 * 2;            // 638,976
  const size_t need_new = h_bytes + P_bytes + small_bytes;        // ~116.6 MiB

  if (ws_size >= need_new) {
    unsigned short* h = (unsigned short*)ws;
    char* P = ws + h_bytes;
    unsigned short* xbf = (unsigned short*)P;
    unsigned short* wiT = (unsigned short*)(P + xbf_bytes);
    unsigned short* woT = (unsigned short*)P;  // overlays xbf/wiT AFTER gemm1
    char* smalls = P + P_bytes;
    float* expw = (float*)smalls;
    float* noopw = expw + (size_t)NE * NTOK;
    int* slot_tok = (int*)(noopw + NTOK);
    float* slot_w = (float*)(slot_tok + (size_t)NE * CAP);

    prologue_kernel<<<NTOK / 4 + 1, 256, 0, stream>>>(x, rw, rb, expw, noopw,
                                                      xbf, out);
    assign_par_kernel<<<NE, 1024, 0, stream>>>(expw, slot_tok, slot_w);
    transpose_bf16_kernel<<<dim3(INTER / 64, HIDDEN / 64, NE), 256, 0, stream>>>(
        wi, wiT, HIDDEN, INTER);
    gemm1_mfma_kernel<<<dim3(INTER / GBN, CAP / GBM, NE), 256, 0, stream>>>(
        xbf, wiT, slot_tok, h);
    // woT overwrites xbf/wiT — safe: stream-ordered after gemm1 completes
    transpose_bf16_kernel<<<dim3(HIDDEN / 64, INTER / 64, NE), 256, 0, stream>>>(
        wo, woT, INTER, HIDDEN);
    gemm2_mfma_kernel<<<dim3(HIDDEN / GBN, CAP / GBM, NE), 256, 0, stream>>>(
        h, woT, slot_tok, slot_w, out);
    return;
  }

  // ---- fallback: round-2 path ----
  const size_t h_full = (size_t)NE * CAP * INTER * 2;
  const size_t h_one = (size_t)CAP * INTER * 2;
  bool full = ws_size >= h_full + small_bytes;
  size_t hb = full ? h_full : h_one;
  unsigned short* h = (unsigned short*)ws;
  float* expw = (float*)(ws + hb);
  float* noopw = expw + (size_t)NE * NTOK;
  int* slot_tok = (int*)(noopw + NTOK);
  float* slot_w = (float*)(slot_tok + (size_t)NE * CAP);

  router_kernel<<<NTOK / 4, 256, 0, stream>>>(x, rw, rb, expw, noopw);
  assign_kernel<<<NE, 64, 0, stream>>>(expw, slot_tok, slot_w);
  noop_kernel<<<(NTOK * (HIDDEN / 4)) / 256, 256, 0, stream>>>(x, noopw, out);
  if (full) {
    gemm1_kernel<<<dim3(INTER / BN, CAP / BM, NE), 256, 0, stream>>>(
        x, wi, slot_tok, h, 0);
    gemm2_kernel<<<dim3(HIDDEN / BN, CAP / BM, NE), 256, 0, stream>>>(
        h, wo, slot_tok, slot_w, out, 0);
  } else {
    for (int e = 0; e < NE; e++) {
      gemm1_kernel<<<dim3(INTER / BN, CAP / BM, 1), 256, 0, stream>>>(
          x, wi, slot_tok, h, e);
      gemm2_kernel<<<dim3(HIDDEN / BN, CAP / BM, 1), 256, 0, stream>>>(
          h, wo, slot_tok, slot_w, out, e);
    }
  }
}

// Round 6
// 423.797 us; speedup vs baseline: 1.0634x; 1.0634x over previous
//
#include <hip/hip_runtime.h>
#include <stdint.h>

#define HIDDEN 1024
#define INTER 2048
#define NEXP 8
#define NE 7
#define NTOK 16384
#define CAP 2048
#define GBM 128
#define GBN 128

typedef __attribute__((ext_vector_type(8))) short short8;
typedef __attribute__((ext_vector_type(4))) float f32x4;

__device__ __forceinline__ unsigned short f2bf(float f) {
  union { float f; unsigned int u; } v;
  v.f = f;
  unsigned int u = v.u;
  unsigned int r = (u + 0x7FFFu + ((u >> 16) & 1u)) >> 16;  // RNE
  return (unsigned short)r;
}

typedef __attribute__((address_space(1))) const unsigned int gu32;
typedef __attribute__((address_space(3))) unsigned int lu32;
__device__ __forceinline__ void gload16(const void* g, void* l) {
  __builtin_amdgcn_global_load_lds((gu32*)g, (lu32*)l, 16, 0, 0);
}

// ==== fused prologue: router + x->bf16 + noop out-init + transpose(Wi) ====
// blocks [0, NTOK/4): router/convert/noop; block NTOK/4: zero pad row;
// blocks (NTOK/4, NTOK/4 + 3584]: Wi [K=1024][N=2048] f32 -> wiT [N][K] bf16.
__global__ __launch_bounds__(256) void prologue_kernel(
    const float* __restrict__ x, const float* __restrict__ rw,
    const float* __restrict__ rb, float* __restrict__ expw,
    float* __restrict__ noopw, unsigned short* __restrict__ xbf,
    float* __restrict__ out, const float* __restrict__ wi,
    unsigned short* __restrict__ wiT) {
  int bx = blockIdx.x;
  int tid = threadIdx.x;
  if (bx > NTOK / 4) {
    // ---- transpose Wi tile 64x64 ----
    int i = bx - (NTOK / 4 + 1);
    int e = i >> 9;           // 512 tiles per expert (16 k-tiles x 32 n-tiles)
    int rem = i & 511;
    int k0 = (rem >> 5) * 64;  // over K=HIDDEN
    int n0 = (rem & 31) * 64;  // over N=INTER
    const float* src = wi + (size_t)e * HIDDEN * INTER;
    unsigned short* dst = wiT + (size_t)e * HIDDEN * INTER;
    __shared__ float tile[64][65];
    int nr = tid & 15, kr = tid >> 4;
#pragma unroll
    for (int ii = 0; ii < 4; ii++) {
      int k = ii * 16 + kr;
      float4 v = *(const float4*)(src + (size_t)(k0 + k) * INTER + n0 + nr * 4);
      tile[k][nr * 4 + 0] = v.x;
      tile[k][nr * 4 + 1] = v.y;
      tile[k][nr * 4 + 2] = v.z;
      tile[k][nr * 4 + 3] = v.w;
    }
    __syncthreads();
    int g = tid & 7, nb = tid >> 3;
#pragma unroll
    for (int ii = 0; ii < 2; ii++) {
      int n = ii * 32 + nb;
      short8 p;
#pragma unroll
      for (int j = 0; j < 8; j++) p[j] = (short)f2bf(tile[g * 8 + j][n]);
      *(short8*)(dst + (size_t)(n0 + n) * HIDDEN + k0 + g * 8) = p;
    }
    return;
  }
  if (bx == NTOK / 4) {
    unsigned int* z = (unsigned int*)(xbf + (size_t)NTOK * HIDDEN);
    z[tid] = 0u;
    z[tid + 256] = 0u;
    return;
  }
  int wid = tid >> 6;
  int lane = tid & 63;
  int token = bx * 4 + wid;
  const float* xr = x + (size_t)token * HIDDEN;
  float4 xv[4];
  float acc[NEXP];
#pragma unroll
  for (int e = 0; e < NEXP; e++) acc[e] = 0.f;
#pragma unroll
  for (int j = 0; j < 4; j++) {
    xv[j] = *(const float4*)(xr + j * 256 + lane * 4);
#pragma unroll
    for (int e = 0; e < NEXP; e++) {
      float4 wv = *(const float4*)(rw + e * HIDDEN + j * 256 + lane * 4);
      acc[e] = fmaf(xv[j].x, wv.x, acc[e]);
      acc[e] = fmaf(xv[j].y, wv.y, acc[e]);
      acc[e] = fmaf(xv[j].z, wv.z, acc[e]);
      acc[e] = fmaf(xv[j].w, wv.w, acc[e]);
    }
  }
#pragma unroll
  for (int e = 0; e < NEXP; e++) {
    float a = acc[e];
#pragma unroll
    for (int off = 32; off > 0; off >>= 1) a += __shfl_xor(a, off);
    acc[e] = a + rb[e];
  }
  float nwv = 0.f;
  if (lane == 0) {
    float m = acc[0];
#pragma unroll
    for (int e = 1; e < NEXP; e++) m = fmaxf(m, acc[e]);
    float w[NEXP];
    float s = 0.f;
#pragma unroll
    for (int e = 0; e < NEXP; e++) { w[e] = expf(acc[e] - m); s += w[e]; }
    float inv = 1.f / s;
#pragma unroll
    for (int e = 0; e < NEXP; e++) w[e] *= inv;
    int t1 = 0;
#pragma unroll
    for (int e = 1; e < NEXP; e++) if (w[e] > w[t1]) t1 = e;
    int t2 = (t1 == 0) ? 1 : 0;
#pragma unroll
    for (int e = 0; e < NEXP; e++) if (e != t1 && w[e] > w[t2]) t2 = e;
    nwv = (t1 == NEXP - 1) ? w[t1] : ((t2 == NEXP - 1) ? w[t2] : 0.f);
    noopw[token] = nwv;
#pragma unroll
    for (int e = 0; e < NE; e++) {
      float v = 0.f;
      if (e == t1) v = w[e];
      if (e == t2) v = w[e];
      expw[(size_t)e * NTOK + token] = v;
    }
  }
  float nw = __shfl(nwv, 0);
  float* orow = out + (size_t)token * HIDDEN;
  unsigned short* brow = xbf + (size_t)token * HIDDEN;
#pragma unroll
  for (int j = 0; j < 4; j++) {
    float4 o = xv[j];
    o.x *= nw; o.y *= nw; o.z *= nw; o.w *= nw;
    *(float4*)(orow + j * 256 + lane * 4) = o;
    ushort4 b;
    b.x = f2bf(xv[j].x); b.y = f2bf(xv[j].y);
    b.z = f2bf(xv[j].z); b.w = f2bf(xv[j].w);
    *(ushort4*)(brow + j * 256 + lane * 4) = b;
  }
}

// ============ parallel assign: 1024-thread block scan per expert ============
__global__ __launch_bounds__(1024) void assign_par_kernel(
    const float* __restrict__ expw, int* __restrict__ slot_tok,
    float* __restrict__ slot_w) {
  int e = blockIdx.x;
  int tid = threadIdx.x;
  int lane = tid & 63, w = tid >> 6;  // 16 waves
  __shared__ int wtot[16];
  const float* we = expw + (size_t)e * NTOK;
  int base = 0;
#pragma unroll 1
  for (int r = 0; r < NTOK / 1024; r++) {
    int t = r * 1024 + tid;
    float wv = we[t];
    bool flag = wv > 0.f;
    unsigned long long mask = __ballot(flag);
    int lp = __popcll(mask & ((1ull << lane) - 1ull));
    if (lane == 0) wtot[w] = __popcll(mask);
    __syncthreads();
    int pre = 0, tot = 0;
#pragma unroll
    for (int i = 0; i < 16; i++) {
      int v = wtot[i];
      pre += (i < w) ? v : 0;
      tot += v;
    }
    int pos = base + pre + lp;
    if (flag && pos < CAP) {
      slot_tok[e * CAP + pos] = t;
      slot_w[e * CAP + pos] = wv;
    }
    base += tot;
    __syncthreads();
    if (base >= CAP) break;  // uniform across block
  }
  int cnt = base < CAP ? base : CAP;
  for (int p = cnt + tid; p < CAP; p += 1024) {
    slot_tok[e * CAP + p] = -1;
    slot_w[e * CAP + p] = 0.f;
  }
}

// ------ standalone transpose (mid path): [K][N] f32 -> [N][K] bf16 ------
__global__ __launch_bounds__(256) void transpose_bf16_kernel(
    const float* __restrict__ in, unsigned short* __restrict__ outp,
    int K, int N) {
  int e = blockIdx.z;
  const float* src = in + (size_t)e * K * N;
  unsigned short* dst = outp + (size_t)e * K * N;
  int k0 = blockIdx.y * 64;
  int n0 = blockIdx.x * 64;
  __shared__ float tile[64][65];
  int tid = threadIdx.x;
  int nr = tid & 15;
  int kr = tid >> 4;
#pragma unroll
  for (int i = 0; i < 4; i++) {
    int k = i * 16 + kr;
    float4 v = *(const float4*)(src + (size_t)(k0 + k) * N + n0 + nr * 4);
    tile[k][nr * 4 + 0] = v.x;
    tile[k][nr * 4 + 1] = v.y;
    tile[k][nr * 4 + 2] = v.z;
    tile[k][nr * 4 + 3] = v.w;
  }
  __syncthreads();
  int g = tid & 7;
  int nb = tid >> 3;
#pragma unroll
  for (int i = 0; i < 2; i++) {
    int n = i * 32 + nb;
    short8 p;
#pragma unroll
    for (int j = 0; j < 8; j++) p[j] = (short)f2bf(tile[g * 8 + j][n]);
    *(short8*)(dst + (size_t)(n0 + n) * K + k0 + g * 8) = p;
  }
}

// ---- gemm1: 128x128 tile, BK=64, 8 waves (512thr), acc 4x2/wave ----
// blockIdx.y >= 16 => fused transpose of Wo [INTER][HIDDEN] -> woT [HIDDEN][INTER]
__global__ __launch_bounds__(512, 4) void gemm1_mfma_kernel(
    const unsigned short* __restrict__ xbf, const unsigned short* __restrict__ wiT,
    const int* __restrict__ slot_tok, unsigned short* __restrict__ h,
    const float* __restrict__ wo, unsigned short* __restrict__ woT) {
  __shared__ __align__(16) unsigned short smem[GBM * 64 + GBN * 64];
  unsigned short* As = smem;
  unsigned short* Bs = smem + GBM * 64;
  int tid = threadIdx.x;
  if (blockIdx.y >= 16) {
    // ---- transpose Wo tile 64x64 (512 threads), reuse smem ----
    int e = blockIdx.z;
    int k0 = (blockIdx.y - 16) * 64;  // over K=INTER (32 tiles)
    int n0 = blockIdx.x * 64;         // over N=HIDDEN (16 tiles)
    const float* src = wo + (size_t)e * INTER * HIDDEN;
    unsigned short* dst = woT + (size_t)e * INTER * HIDDEN;
    float* tile = (float*)smem;  // 64*65 floats = 16640B <= 32768B
    int nr = tid & 15, kr = tid >> 4;  // kr 0..31
#pragma unroll
    for (int ii = 0; ii < 2; ii++) {
      int k = ii * 32 + kr;
      float4 v = *(const float4*)(src + (size_t)(k0 + k) * HIDDEN + n0 + nr * 4);
      tile[k * 65 + nr * 4 + 0] = v.x;
      tile[k * 65 + nr * 4 + 1] = v.y;
      tile[k * 65 + nr * 4 + 2] = v.z;
      tile[k * 65 + nr * 4 + 3] = v.w;
    }
    __syncthreads();
    int g = tid & 7, n = tid >> 3;  // n 0..63
    short8 p;
#pragma unroll
    for (int j = 0; j < 8; j++) p[j] = (short)f2bf(tile[(g * 8 + j) * 65 + n]);
    *(short8*)(dst + (size_t)(n0 + n) * INTER + k0 + g * 8) = p;
    return;
  }
  // ---- gemm part; XCD-bijective swizzle over nwg=1792, chunk=224 ----
  int orig = blockIdx.x + (blockIdx.y << 4) + (blockIdx.z << 8);
  int swz = (orig & 7) * 224 + (orig >> 3);
  int bxi = swz & 15, byi = (swz >> 4) & 15, bzi = swz >> 8;
  int e = bzi;
  const unsigned short* be = wiT + (size_t)e * HIDDEN * INTER;
  unsigned short* he = h + (size_t)e * CAP * INTER;
  int bm0 = byi * GBM;
  int bn0 = bxi * GBN;
  int lane = tid & 63, w = tid >> 6;
  int wm = w >> 2, wn = w & 3;

  const unsigned short* aptr[2];
  const unsigned short* bptr[2];
#pragma unroll
  for (int c = 0; c < 2; c++) {
    int slot = c * 512 + tid;
    int r = slot >> 3;
    int gb = slot & 7;
    int g = gb ^ (r & 7);
    int tok = slot_tok[e * CAP + bm0 + r];
    int row = tok < 0 ? NTOK : tok;
    aptr[c] = xbf + (size_t)row * HIDDEN + g * 8;
    bptr[c] = be + (size_t)(bn0 + r) * HIDDEN + g * 8;
  }

  f32x4 acc[4][2];
#pragma unroll
  for (int i = 0; i < 4; i++)
#pragma unroll
    for (int j = 0; j < 2; j++) acc[i][j] = (f32x4){0.f, 0.f, 0.f, 0.f};

  for (int k0 = 0; k0 < HIDDEN; k0 += 64) {
#pragma unroll
    for (int c = 0; c < 2; c++) {
      gload16(aptr[c] + k0, As + (c * 512 + tid) * 8);
      gload16(bptr[c] + k0, Bs + (c * 512 + tid) * 8);
    }
    __syncthreads();
#pragma unroll
    for (int kk = 0; kk < 2; kk++) {
      short8 a[4], b[2];
#pragma unroll
      for (int fm = 0; fm < 4; fm++) {
        int r = wm * 64 + fm * 16 + (lane & 15);
        int gb = (kk * 4 + (lane >> 4)) ^ (r & 7);
        a[fm] = *(const short8*)&As[r * 64 + gb * 8];
      }
#pragma unroll
      for (int fn = 0; fn < 2; fn++) {
        int n = wn * 32 + fn * 16 + (lane & 15);
        int gb = (kk * 4 + (lane >> 4)) ^ (n & 7);
        b[fn] = *(const short8*)&Bs[n * 64 + gb * 8];
      }
#pragma unroll
      for (int fm = 0; fm < 4; fm++)
#pragma unroll
        for (int fn = 0; fn < 2; fn++)
          acc[fm][fn] = __builtin_amdgcn_mfma_f32_16x16x32_bf16(
              a[fm], b[fn], acc[fm][fn], 0, 0, 0);
    }
    __syncthreads();
  }
#pragma unroll
  for (int fm = 0; fm < 4; fm++)
#pragma unroll
    for (int r4 = 0; r4 < 4; r4++) {
      int m = bm0 + wm * 64 + fm * 16 + ((lane >> 4) << 2) + r4;
#pragma unroll
      for (int fn = 0; fn < 2; fn++) {
        int n = bn0 + wn * 32 + fn * 16 + (lane & 15);
        float v = acc[fm][fn][r4];
        he[(size_t)m * INTER + n] = f2bf(v > 0.f ? v : 0.f);
      }
    }
}

// ---- gemm2: 128x128 tile, BK=64, 8 waves, acc 4x2/wave, atomic scatter ----
__global__ __launch_bounds__(512, 4) void gemm2_mfma_kernel(
    const unsigned short* __restrict__ h, const unsigned short* __restrict__ woT,
    const int* __restrict__ slot_tok, const float* __restrict__ slot_w,
    float* __restrict__ out) {
  // grid (8,16,7): nwg=896, chunk=112
  int orig = blockIdx.x + (blockIdx.y << 3) + (blockIdx.z << 7);
  int swz = (orig & 7) * 112 + (orig >> 3);
  int bxi = swz & 7, byi = (swz >> 3) & 15, bzi = swz >> 7;
  int e = bzi;
  const unsigned short* ae = h + (size_t)e * CAP * INTER;
  const unsigned short* be = woT + (size_t)e * INTER * HIDDEN;  // [HIDDEN][INTER]
  int bm0 = byi * GBM;
  int bn0 = bxi * GBN;
  __shared__ __align__(16) unsigned short smem[GBM * 64 + GBN * 64];
  unsigned short* As = smem;
  unsigned short* Bs = smem + GBM * 64;
  int tid = threadIdx.x;
  int lane = tid & 63, w = tid >> 6;
  int wm = w >> 2, wn = w & 3;

  const unsigned short* aptr[2];
  const unsigned short* bptr[2];
#pragma unroll
  for (int c = 0; c < 2; c++) {
    int slot = c * 512 + tid;
    int r = slot >> 3;
    int gb = slot & 7;
    int g = gb ^ (r & 7);
    aptr[c] = ae + (size_t)(bm0 + r) * INTER + g * 8;
    bptr[c] = be + (size_t)(bn0 + r) * INTER + g * 8;
  }

  f32x4 acc[4][2];
#pragma unroll
  for (int i = 0; i < 4; i++)
#pragma unroll
    for (int j = 0; j < 2; j++) acc[i][j] = (f32x4){0.f, 0.f, 0.f, 0.f};

  for (int k0 = 0; k0 < INTER; k0 += 64) {
#pragma unroll
    for (int c = 0; c < 2; c++) {
      gload16(aptr[c] + k0, As + (c * 512 + tid) * 8);
      gload16(bptr[c] + k0, Bs + (c * 512 + tid) * 8);
    }
    __syncthreads();
#pragma unroll
    for (int kk = 0; kk < 2; kk++) {
      short8 a[4], b[2];
#pragma unroll
      for (int fm = 0; fm < 4; fm++) {
        int r = wm * 64 + fm * 16 + (lane & 15);
        int gb = (kk * 4 + (lane >> 4)) ^ (r & 7);
        a[fm] = *(const short8*)&As[r * 64 + gb * 8];
      }
#pragma unroll
      for (int fn = 0; fn < 2; fn++) {
        int n = wn * 32 + fn * 16 + (lane & 15);
        int gb = (kk * 4 + (lane >> 4)) ^ (n & 7);
        b[fn] = *(const short8*)&Bs[n * 64 + gb * 8];
      }
#pragma unroll
      for (int fm = 0; fm < 4; fm++)
#pragma unroll
        for (int fn = 0; fn < 2; fn++)
          acc[fm][fn] = __builtin_amdgcn_mfma_f32_16x16x32_bf16(
              a[fm], b[fn], acc[fm][fn], 0, 0, 0);
    }
    __syncthreads();
  }
#pragma unroll
  for (int fm = 0; fm < 4; fm++)
#pragma unroll
    for (int r4 = 0; r4 < 4; r4++) {
      int m = bm0 + wm * 64 + fm * 16 + ((lane >> 4) << 2) + r4;
      int tok = slot_tok[e * CAP + m];
      float sw = slot_w[e * CAP + m];
      if (tok >= 0) {
#pragma unroll
        for (int fn = 0; fn < 2; fn++) {
          int n = bn0 + wn * 32 + fn * 16 + (lane & 15);
          unsafeAtomicAdd(out + (size_t)tok * HIDDEN + n, acc[fm][fn][r4] * sw);
        }
      }
    }
}

extern "C" void kernel_launch(void* const* d_in, const int* in_sizes, int n_in,
                              void* d_out, int out_size, void* d_ws, size_t ws_size,
                              hipStream_t stream) {
  const float* x = (const float*)d_in[0];
  const float* rw = (const float*)d_in[1];
  const float* rb = (const float*)d_in[2];
  const float* wi = (const float*)d_in[3];
  const float* wo = (const float*)d_in[4];
  float* out = (float*)d_out;
  char* ws = (char*)d_ws;

  const size_t h_bytes = (size_t)NE * CAP * INTER * 2;       // 58,720,256
  const size_t xbf_bytes = (size_t)(NTOK + 1) * HIDDEN * 2;  // 33,556,480
  const size_t wT_bytes = (size_t)NE * HIDDEN * INTER * 2;   // 29,360,128
  const size_t small_bytes = (size_t)NE * NTOK * 4 + (size_t)NTOK * 4 +
                             (size_t)NE * CAP * 4 * 2;       // 638,976
  const size_t need_mid = h_bytes + xbf_bytes + wT_bytes + small_bytes;
  const size_t need_full = need_mid + wT_bytes;  // separate woT (no overlay)

  bool fullp = ws_size >= need_full;
  unsigned short* h = (unsigned short*)ws;
  unsigned short* xbf = (unsigned short*)(ws + h_bytes);
  unsigned short* wiT = (unsigned short*)(ws + h_bytes + xbf_bytes);
  unsigned short* woT =
      fullp ? (unsigned short*)(ws + h_bytes + xbf_bytes + wT_bytes)
            : (unsigned short*)(ws + h_bytes);  // overlays xbf/wiT (serial)
  char* smalls = ws + (fullp ? need_full : need_mid) - small_bytes;
  float* expw = (float*)smalls;
  float* noopw = expw + (size_t)NE * NTOK;
  int* slot_tok = (int*)(noopw + NTOK);
  float* slot_w = (float*)(slot_tok + (size_t)NE * CAP);

  const int NPRO = NTOK / 4 + 1 + NE * 512;  // router + pad + Wi-transpose tiles
  prologue_kernel<<<NPRO, 256, 0, stream>>>(x, rw, rb, expw, noopw, xbf, out,
                                            wi, wiT);
  assign_par_kernel<<<NE, 1024, 0, stream>>>(expw, slot_tok, slot_w);
  if (fullp) {
    // gemm1 + fused Wo-transpose (blocks y>=16 write separate woT buffer)
    gemm1_mfma_kernel<<<dim3(16, 48, NE), 512, 0, stream>>>(
        xbf, wiT, slot_tok, h, wo, woT);
  } else {
    gemm1_mfma_kernel<<<dim3(16, 16, NE), 512, 0, stream>>>(
        xbf, wiT, slot_tok, h, wo, woT);
    // woT overlays xbf/wiT — must run after gemm1 (stream-ordered)
    transpose_bf16_kernel<<<dim3(HIDDEN / 64, INTER / 64, NE), 256, 0, stream>>>(
        wo, woT, INTER, HIDDEN);
  }
  gemm2_mfma_kernel<<<dim3(8, 16, NE), 512, 0, stream>>>(
      h, woT, slot_tok, slot_w, out);
}

// Round 7
// 410.619 us; speedup vs baseline: 1.0975x; 1.0321x over previous
//
#include <hip/hip_runtime.h>
#include <stdint.h>

#define HIDDEN 1024
#define INTER 2048
#define NEXP 8
#define NE 7
#define NTOK 16384
#define CAP 2048
#define GBM 128
#define GBN 128

typedef __attribute__((ext_vector_type(8))) short short8;
typedef __attribute__((ext_vector_type(4))) float f32x4;

__device__ __forceinline__ unsigned short f2bf(float f) {
  union { float f; unsigned int u; } v;
  v.f = f;
  unsigned int u = v.u;
  unsigned int r = (u + 0x7FFFu + ((u >> 16) & 1u)) >> 16;  // RNE
  return (unsigned short)r;
}

typedef __attribute__((address_space(1))) const unsigned int gu32;
typedef __attribute__((address_space(3))) unsigned int lu32;
__device__ __forceinline__ void gload16(const void* g, void* l) {
  __builtin_amdgcn_global_load_lds((gu32*)g, (lu32*)l, 16, 0, 0);
}

// ==== fused prologue: router + x->bf16 + noop out-init + transpose(Wi) ====
__global__ __launch_bounds__(256) void prologue_kernel(
    const float* __restrict__ x, const float* __restrict__ rw,
    const float* __restrict__ rb, float* __restrict__ expw,
    float* __restrict__ noopw, unsigned short* __restrict__ xbf,
    float* __restrict__ out, const float* __restrict__ wi,
    unsigned short* __restrict__ wiT) {
  int bx = blockIdx.x;
  int tid = threadIdx.x;
  if (bx > NTOK / 4) {
    // ---- transpose Wi tile 64x64 ----
    int i = bx - (NTOK / 4 + 1);
    int e = i >> 9;            // 512 tiles per expert
    int rem = i & 511;
    int k0 = (rem >> 5) * 64;  // over K=HIDDEN
    int n0 = (rem & 31) * 64;  // over N=INTER
    const float* src = wi + (size_t)e * HIDDEN * INTER;
    unsigned short* dst = wiT + (size_t)e * HIDDEN * INTER;
    __shared__ float tile[64][65];
    int nr = tid & 15, kr = tid >> 4;
#pragma unroll
    for (int ii = 0; ii < 4; ii++) {
      int k = ii * 16 + kr;
      float4 v = *(const float4*)(src + (size_t)(k0 + k) * INTER + n0 + nr * 4);
      tile[k][nr * 4 + 0] = v.x;
      tile[k][nr * 4 + 1] = v.y;
      tile[k][nr * 4 + 2] = v.z;
      tile[k][nr * 4 + 3] = v.w;
    }
    __syncthreads();
    int g = tid & 7, nb = tid >> 3;
#pragma unroll
    for (int ii = 0; ii < 2; ii++) {
      int n = ii * 32 + nb;
      short8 p;
#pragma unroll
      for (int j = 0; j < 8; j++) p[j] = (short)f2bf(tile[g * 8 + j][n]);
      *(short8*)(dst + (size_t)(n0 + n) * HIDDEN + k0 + g * 8) = p;
    }
    return;
  }
  if (bx == NTOK / 4) {
    unsigned int* z = (unsigned int*)(xbf + (size_t)NTOK * HIDDEN);
    z[tid] = 0u;
    z[tid + 256] = 0u;
    return;
  }
  int wid = tid >> 6;
  int lane = tid & 63;
  int token = bx * 4 + wid;
  const float* xr = x + (size_t)token * HIDDEN;
  float4 xv[4];
  float acc[NEXP];
#pragma unroll
  for (int e = 0; e < NEXP; e++) acc[e] = 0.f;
#pragma unroll
  for (int j = 0; j < 4; j++) {
    xv[j] = *(const float4*)(xr + j * 256 + lane * 4);
#pragma unroll
    for (int e = 0; e < NEXP; e++) {
      float4 wv = *(const float4*)(rw + e * HIDDEN + j * 256 + lane * 4);
      acc[e] = fmaf(xv[j].x, wv.x, acc[e]);
      acc[e] = fmaf(xv[j].y, wv.y, acc[e]);
      acc[e] = fmaf(xv[j].z, wv.z, acc[e]);
      acc[e] = fmaf(xv[j].w, wv.w, acc[e]);
    }
  }
#pragma unroll
  for (int e = 0; e < NEXP; e++) {
    float a = acc[e];
#pragma unroll
    for (int off = 32; off > 0; off >>= 1) a += __shfl_xor(a, off);
    acc[e] = a + rb[e];
  }
  float nwv = 0.f;
  if (lane == 0) {
    float m = acc[0];
#pragma unroll
    for (int e = 1; e < NEXP; e++) m = fmaxf(m, acc[e]);
    float w[NEXP];
    float s = 0.f;
#pragma unroll
    for (int e = 0; e < NEXP; e++) { w[e] = expf(acc[e] - m); s += w[e]; }
    float inv = 1.f / s;
#pragma unroll
    for (int e = 0; e < NEXP; e++) w[e] *= inv;
    int t1 = 0;
#pragma unroll
    for (int e = 1; e < NEXP; e++) if (w[e] > w[t1]) t1 = e;
    int t2 = (t1 == 0) ? 1 : 0;
#pragma unroll
    for (int e = 0; e < NEXP; e++) if (e != t1 && w[e] > w[t2]) t2 = e;
    nwv = (t1 == NEXP - 1) ? w[t1] : ((t2 == NEXP - 1) ? w[t2] : 0.f);
    noopw[token] = nwv;
#pragma unroll
    for (int e = 0; e < NE; e++) {
      float v = 0.f;
      if (e == t1) v = w[e];
      if (e == t2) v = w[e];
      expw[(size_t)e * NTOK + token] = v;
    }
  }
  float nw = __shfl(nwv, 0);
  float* orow = out + (size_t)token * HIDDEN;
  unsigned short* brow = xbf + (size_t)token * HIDDEN;
#pragma unroll
  for (int j = 0; j < 4; j++) {
    float4 o = xv[j];
    o.x *= nw; o.y *= nw; o.z *= nw; o.w *= nw;
    *(float4*)(orow + j * 256 + lane * 4) = o;
    ushort4 b;
    b.x = f2bf(xv[j].x); b.y = f2bf(xv[j].y);
    b.z = f2bf(xv[j].z); b.w = f2bf(xv[j].w);
    *(ushort4*)(brow + j * 256 + lane * 4) = b;
  }
}

// ============ parallel assign: 1024-thread block scan per expert ============
__global__ __launch_bounds__(1024) void assign_par_kernel(
    const float* __restrict__ expw, int* __restrict__ slot_tok,
    float* __restrict__ slot_w) {
  int e = blockIdx.x;
  int tid = threadIdx.x;
  int lane = tid & 63, w = tid >> 6;  // 16 waves
  __shared__ int wtot[16];
  const float* we = expw + (size_t)e * NTOK;
  int base = 0;
#pragma unroll 1
  for (int r = 0; r < NTOK / 1024; r++) {
    int t = r * 1024 + tid;
    float wv = we[t];
    bool flag = wv > 0.f;
    unsigned long long mask = __ballot(flag);
    int lp = __popcll(mask & ((1ull << lane) - 1ull));
    if (lane == 0) wtot[w] = __popcll(mask);
    __syncthreads();
    int pre = 0, tot = 0;
#pragma unroll
    for (int i = 0; i < 16; i++) {
      int v = wtot[i];
      pre += (i < w) ? v : 0;
      tot += v;
    }
    int pos = base + pre + lp;
    if (flag && pos < CAP) {
      slot_tok[e * CAP + pos] = t;
      slot_w[e * CAP + pos] = wv;
    }
    base += tot;
    __syncthreads();
    if (base >= CAP) break;  // uniform across block
  }
  int cnt = base < CAP ? base : CAP;
  for (int p = cnt + tid; p < CAP; p += 1024) {
    slot_tok[e * CAP + p] = -1;
    slot_w[e * CAP + p] = 0.f;
  }
}

// ------ standalone transpose (mid path): [K][N] f32 -> [N][K] bf16 ------
__global__ __launch_bounds__(256) void transpose_bf16_kernel(
    const float* __restrict__ in, unsigned short* __restrict__ outp,
    int K, int N) {
  int e = blockIdx.z;
  const float* src = in + (size_t)e * K * N;
  unsigned short* dst = outp + (size_t)e * K * N;
  int k0 = blockIdx.y * 64;
  int n0 = blockIdx.x * 64;
  __shared__ float tile[64][65];
  int tid = threadIdx.x;
  int nr = tid & 15;
  int kr = tid >> 4;
#pragma unroll
  for (int i = 0; i < 4; i++) {
    int k = i * 16 + kr;
    float4 v = *(const float4*)(src + (size_t)(k0 + k) * N + n0 + nr * 4);
    tile[k][nr * 4 + 0] = v.x;
    tile[k][nr * 4 + 1] = v.y;
    tile[k][nr * 4 + 2] = v.z;
    tile[k][nr * 4 + 3] = v.w;
  }
  __syncthreads();
  int g = tid & 7;
  int nb = tid >> 3;
#pragma unroll
  for (int i = 0; i < 2; i++) {
    int n = i * 32 + nb;
    short8 p;
#pragma unroll
    for (int j = 0; j < 8; j++) p[j] = (short)f2bf(tile[g * 8 + j][n]);
    *(short8*)(dst + (size_t)(n0 + n) * K + k0 + g * 8) = p;
  }
}

// ---- gemm1: 128x128, BK=64, 8 waves, LDS dbuf + counted-vmcnt pipeline ----
// blockIdx.y >= 16 => fused transpose of Wo [INTER][HIDDEN] -> woT [HIDDEN][INTER]
__global__ __launch_bounds__(512, 4) void gemm1_mfma_kernel(
    const unsigned short* __restrict__ xbf, const unsigned short* __restrict__ wiT,
    const int* __restrict__ slot_tok, unsigned short* __restrict__ h,
    const float* __restrict__ wo, unsigned short* __restrict__ woT) {
  __shared__ __align__(16) unsigned short As[2][GBM * 64];
  __shared__ __align__(16) unsigned short Bs[2][GBN * 64];
  int tid = threadIdx.x;
  if (blockIdx.y >= 16) {
    // ---- transpose Wo tile 64x64 (512 threads), reuse As as scratch ----
    int e = blockIdx.z;
    int k0 = (blockIdx.y - 16) * 64;  // over K=INTER (32 tiles)
    int n0 = blockIdx.x * 64;         // over N=HIDDEN (16 tiles)
    const float* src = wo + (size_t)e * INTER * HIDDEN;
    unsigned short* dst = woT + (size_t)e * INTER * HIDDEN;
    float* tile = (float*)As;  // 64*65 floats = 16640B <= 32KB contiguous
    int nr = tid & 15, kr = tid >> 4;  // kr 0..31
#pragma unroll
    for (int ii = 0; ii < 2; ii++) {
      int k = ii * 32 + kr;
      float4 v = *(const float4*)(src + (size_t)(k0 + k) * HIDDEN + n0 + nr * 4);
      tile[k * 65 + nr * 4 + 0] = v.x;
      tile[k * 65 + nr * 4 + 1] = v.y;
      tile[k * 65 + nr * 4 + 2] = v.z;
      tile[k * 65 + nr * 4 + 3] = v.w;
    }
    __syncthreads();
    int g = tid & 7, n = tid >> 3;  // n 0..63
    short8 p;
#pragma unroll
    for (int j = 0; j < 8; j++) p[j] = (short)f2bf(tile[(g * 8 + j) * 65 + n]);
    *(short8*)(dst + (size_t)(n0 + n) * INTER + k0 + g * 8) = p;
    return;
  }
  // ---- gemm part; XCD-bijective swizzle over nwg=1792, chunk=224 ----
  int orig = blockIdx.x + (blockIdx.y << 4) + (blockIdx.z << 8);
  int swz = (orig & 7) * 224 + (orig >> 3);
  int bxi = swz & 15, byi = (swz >> 4) & 15, bzi = swz >> 8;
  int e = bzi;
  const unsigned short* be = wiT + (size_t)e * HIDDEN * INTER;
  unsigned short* he = h + (size_t)e * CAP * INTER;
  int bm0 = byi * GBM;
  int bn0 = bxi * GBN;
  int lane = tid & 63, w = tid >> 6;
  int wm = w >> 2, wn = w & 3;

  const unsigned short* aptr[2];
  const unsigned short* bptr[2];
#pragma unroll
  for (int c = 0; c < 2; c++) {
    int slot = c * 512 + tid;
    int r = slot >> 3;
    int gb = slot & 7;
    int g = gb ^ (r & 7);
    int tok = slot_tok[e * CAP + bm0 + r];
    int row = tok < 0 ? NTOK : tok;
    aptr[c] = xbf + (size_t)row * HIDDEN + g * 8;
    bptr[c] = be + (size_t)(bn0 + r) * HIDDEN + g * 8;
  }

  f32x4 acc[4][2];
#pragma unroll
  for (int i = 0; i < 4; i++)
#pragma unroll
    for (int j = 0; j < 2; j++) acc[i][j] = (f32x4){0.f, 0.f, 0.f, 0.f};

  auto stageT = [&](int k0, int buf) {
#pragma unroll
    for (int c = 0; c < 2; c++) {
      gload16(aptr[c] + k0, &As[buf][(c * 512 + tid) * 8]);
      gload16(bptr[c] + k0, &Bs[buf][(c * 512 + tid) * 8]);
    }
  };
  auto computeT = [&](int buf) {
#pragma unroll
    for (int kk = 0; kk < 2; kk++) {
      short8 a[4], b[2];
#pragma unroll
      for (int fm = 0; fm < 4; fm++) {
        int r = wm * 64 + fm * 16 + (lane & 15);
        int gb = (kk * 4 + (lane >> 4)) ^ (r & 7);
        a[fm] = *(const short8*)&As[buf][r * 64 + gb * 8];
      }
#pragma unroll
      for (int fn = 0; fn < 2; fn++) {
        int n = wn * 32 + fn * 16 + (lane & 15);
        int gb = (kk * 4 + (lane >> 4)) ^ (n & 7);
        b[fn] = *(const short8*)&Bs[buf][n * 64 + gb * 8];
      }
#pragma unroll
      for (int fm = 0; fm < 4; fm++)
#pragma unroll
        for (int fn = 0; fn < 2; fn++)
          acc[fm][fn] = __builtin_amdgcn_mfma_f32_16x16x32_bf16(
              a[fm], b[fn], acc[fm][fn], 0, 0, 0);
    }
  };

  const int nt = HIDDEN / 64;  // 16
  stageT(0, 0);
  int cur = 0;
#pragma unroll 1
  for (int t = 0; t < nt; t++) {
    if (t + 1 < nt) {
      stageT((t + 1) * 64, cur ^ 1);
      asm volatile("s_waitcnt vmcnt(4)" ::: "memory");  // tile t's 4 loads done
    } else {
      asm volatile("s_waitcnt vmcnt(0)" ::: "memory");
    }
    __builtin_amdgcn_s_barrier();
    computeT(cur);
    __builtin_amdgcn_s_barrier();  // fence buffer reuse before next stage
    cur ^= 1;
  }
#pragma unroll
  for (int fm = 0; fm < 4; fm++)
#pragma unroll
    for (int r4 = 0; r4 < 4; r4++) {
      int m = bm0 + wm * 64 + fm * 16 + ((lane >> 4) << 2) + r4;
#pragma unroll
      for (int fn = 0; fn < 2; fn++) {
        int n = bn0 + wn * 32 + fn * 16 + (lane & 15);
        float v = acc[fm][fn][r4];
        he[(size_t)m * INTER + n] = f2bf(v > 0.f ? v : 0.f);
      }
    }
}

// ---- gemm2: 128x128, BK=64, 8 waves, dbuf + counted vmcnt, atomic scatter ----
__global__ __launch_bounds__(512, 4) void gemm2_mfma_kernel(
    const unsigned short* __restrict__ h, const unsigned short* __restrict__ woT,
    const int* __restrict__ slot_tok, const float* __restrict__ slot_w,
    float* __restrict__ out) {
  // grid (8,16,7): nwg=896, chunk=112
  int orig = blockIdx.x + (blockIdx.y << 3) + (blockIdx.z << 7);
  int swz = (orig & 7) * 112 + (orig >> 3);
  int bxi = swz & 7, byi = (swz >> 3) & 15, bzi = swz >> 7;
  int e = bzi;
  const unsigned short* ae = h + (size_t)e * CAP * INTER;
  const unsigned short* be = woT + (size_t)e * INTER * HIDDEN;  // [HIDDEN][INTER]
  int bm0 = byi * GBM;
  int bn0 = bxi * GBN;
  __shared__ __align__(16) unsigned short As[2][GBM * 64];
  __shared__ __align__(16) unsigned short Bs[2][GBN * 64];
  int tid = threadIdx.x;
  int lane = tid & 63, w = tid >> 6;
  int wm = w >> 2, wn = w & 3;

  const unsigned short* aptr[2];
  const unsigned short* bptr[2];
#pragma unroll
  for (int c = 0; c < 2; c++) {
    int slot = c * 512 + tid;
    int r = slot >> 3;
    int gb = slot & 7;
    int g = gb ^ (r & 7);
    aptr[c] = ae + (size_t)(bm0 + r) * INTER + g * 8;
    bptr[c] = be + (size_t)(bn0 + r) * INTER + g * 8;
  }

  f32x4 acc[4][2];
#pragma unroll
  for (int i = 0; i < 4; i++)
#pragma unroll
    for (int j = 0; j < 2; j++) acc[i][j] = (f32x4){0.f, 0.f, 0.f, 0.f};

  auto stageT = [&](int k0, int buf) {
#pragma unroll
    for (int c = 0; c < 2; c++) {
      gload16(aptr[c] + k0, &As[buf][(c * 512 + tid) * 8]);
      gload16(bptr[c] + k0, &Bs[buf][(c * 512 + tid) * 8]);
    }
  };
  auto computeT = [&](int buf) {
#pragma unroll
    for (int kk = 0; kk < 2; kk++) {
      short8 a[4], b[2];
#pragma unroll
      for (int fm = 0; fm < 4; fm++) {
        int r = wm * 64 + fm * 16 + (lane & 15);
        int gb = (kk * 4 + (lane >> 4)) ^ (r & 7);
        a[fm] = *(const short8*)&As[buf][r * 64 + gb * 8];
      }
#pragma unroll
      for (int fn = 0; fn < 2; fn++) {
        int n = wn * 32 + fn * 16 + (lane & 15);
        int gb = (kk * 4 + (lane >> 4)) ^ (n & 7);
        b[fn] = *(const short8*)&Bs[buf][n * 64 + gb * 8];
      }
#pragma unroll
      for (int fm = 0; fm < 4; fm++)
#pragma unroll
        for (int fn = 0; fn < 2; fn++)
          acc[fm][fn] = __builtin_amdgcn_mfma_f32_16x16x32_bf16(
              a[fm], b[fn], acc[fm][fn], 0, 0, 0);
    }
  };

  const int nt = INTER / 64;  // 32
  stageT(0, 0);
  int cur = 0;
#pragma unroll 1
  for (int t = 0; t < nt; t++) {
    if (t + 1 < nt) {
      stageT((t + 1) * 64, cur ^ 1);
      asm volatile("s_waitcnt vmcnt(4)" ::: "memory");
    } else {
      asm volatile("s_waitcnt vmcnt(0)" ::: "memory");
    }
    __builtin_amdgcn_s_barrier();
    computeT(cur);
    __builtin_amdgcn_s_barrier();
    cur ^= 1;
  }
#pragma unroll
  for (int fm = 0; fm < 4; fm++)
#pragma unroll
    for (int r4 = 0; r4 < 4; r4++) {
      int m = bm0 + wm * 64 + fm * 16 + ((lane >> 4) << 2) + r4;
      int tok = slot_tok[e * CAP + m];
      float sw = slot_w[e * CAP + m];
      if (tok >= 0) {
#pragma unroll
        for (int fn = 0; fn < 2; fn++) {
          int n = bn0 + wn * 32 + fn * 16 + (lane & 15);
          unsafeAtomicAdd(out + (size_t)tok * HIDDEN + n, acc[fm][fn][r4] * sw);
        }
      }
    }
}

extern "C" void kernel_launch(void* const* d_in, const int* in_sizes, int n_in,
                              void* d_out, int out_size, void* d_ws, size_t ws_size,
                              hipStream_t stream) {
  const float* x = (const float*)d_in[0];
  const float* rw = (const float*)d_in[1];
  const float* rb = (const float*)d_in[2];
  const float* wi = (const float*)d_in[3];
  const float* wo = (const float*)d_in[4];
  float* out = (float*)d_out;
  char* ws = (char*)d_ws;

  const size_t h_bytes = (size_t)NE * CAP * INTER * 2;       // 58,720,256
  const size_t xbf_bytes = (size_t)(NTOK + 1) * HIDDEN * 2;  // 33,556,480
  const size_t wT_bytes = (size_t)NE * HIDDEN * INTER * 2;   // 29,360,128
  const size_t small_bytes = (size_t)NE * NTOK * 4 + (size_t)NTOK * 4 +
                             (size_t)NE * CAP * 4 * 2;       // 638,976
  const size_t need_mid = h_bytes + xbf_bytes + wT_bytes + small_bytes;
  const size_t need_full = need_mid + wT_bytes;  // separate woT (no overlay)

  bool fullp = ws_size >= need_full;
  unsigned short* h = (unsigned short*)ws;
  unsigned short* xbf = (unsigned short*)(ws + h_bytes);
  unsigned short* wiT = (unsigned short*)(ws + h_bytes + xbf_bytes);
  unsigned short* woT =
      fullp ? (unsigned short*)(ws + h_bytes + xbf_bytes + wT_bytes)
            : (unsigned short*)(ws + h_bytes);  // overlays xbf/wiT (serial)
  char* smalls = ws + (fullp ? need_full : need_mid) - small_bytes;
  float* expw = (float*)smalls;
  float* noopw = expw + (size_t)NE * NTOK;
  int* slot_tok = (int*)(noopw + NTOK);
  float* slot_w = (float*)(slot_tok + (size_t)NE * CAP);

  const int NPRO = NTOK / 4 + 1 + NE * 512;  // router + pad + Wi-transpose tiles
  prologue_kernel<<<NPRO, 256, 0, stream>>>(x, rw, rb, expw, noopw, xbf, out,
                                            wi, wiT);
  assign_par_kernel<<<NE, 1024, 0, stream>>>(expw, slot_tok, slot_w);
  if (fullp) {
    // gemm1 + fused Wo-transpose (blocks y>=16 write separate woT buffer)
    gemm1_mfma_kernel<<<dim3(16, 48, NE), 512, 0, stream>>>(
        xbf, wiT, slot_tok, h, wo, woT);
  } else {
    gemm1_mfma_kernel<<<dim3(16, 16, NE), 512, 0, stream>>>(
        xbf, wiT, slot_tok, h, wo, woT);
    transpose_bf16_kernel<<<dim3(HIDDEN / 64, INTER / 64, NE), 256, 0, stream>>>(
        wo, woT, INTER, HIDDEN);
  }
  gemm2_mfma_kernel<<<dim3(8, 16, NE), 512, 0, stream>>>(
      h, woT, slot_tok, slot_w, out);
}